// Round 1
// baseline (508.583 us; speedup 1.0000x reference)
//
#include <hip/hip_runtime.h>
#include <hip/hip_bf16.h>

#define NB 2
#define L 256
#define H 8
#define D 64
#define E 512
#define NL (NB * L)
#define RSQRT2 0.70710678118654752f

// ---------------- K0: transpose Wout [E][E] -> WoutT [c][e] ----------------
__global__ __launch_bounds__(256) void k0_transpose(const float* __restrict__ Wout,
                                                    float* __restrict__ WoutT) {
    __shared__ float tile[64][65];
    int t = threadIdx.x;
    int bi = blockIdx.x >> 3;   // e-tile
    int bj = blockIdx.x & 7;    // c-tile
    int tx = t & 63, ty = t >> 6;  // ty 0..3
#pragma unroll
    for (int m = 0; m < 16; m++) {
        int el = ty + (m << 2);
        tile[el][tx] = Wout[(size_t)(bi * 64 + el) * E + bj * 64 + tx];
    }
    __syncthreads();
#pragma unroll
    for (int m = 0; m < 16; m++) {
        int cl = ty + (m << 2);
        WoutT[(size_t)(bj * 64 + cl) * E + bi * 64 + tx] = tile[tx][cl];
    }
}

// ---------------- K1: per-(n,l) projections ----------------
__device__ __forceinline__ float dot64(const float* __restrict__ a,
                                       const float* __restrict__ w) {
    const float4* a4 = (const float4*)a;
    const float4* w4 = (const float4*)w;
    float acc = 0.f;
#pragma unroll
    for (int j = 0; j < 16; j++) {
        float4 x = a4[j], y = w4[j];
        acc = fmaf(x.x, y.x, acc);
        acc = fmaf(x.y, y.y, acc);
        acc = fmaf(x.z, y.z, acc);
        acc = fmaf(x.w, y.w, acc);
    }
    return acc;
}

__global__ __launch_bounds__(256) void k1_proj(
    const float* __restrict__ values, const float* __restrict__ keys,
    const float* __restrict__ query, const float* __restrict__ pos,
    const float* __restrict__ Wv, const float* __restrict__ Wk,
    const float* __restrict__ Wq, const float* __restrict__ Wpq,
    const float* __restrict__ Wpk, const float* __restrict__ Wrk,
    const float* __restrict__ Wrq,
    float* __restrict__ qv_ws, float* __restrict__ kv_ws,
    float* __restrict__ vv_ws, float* __restrict__ pq_ws,
    float* __restrict__ pk_ws, float* __restrict__ qrk_ws,
    float* __restrict__ krq_ws) {
    __shared__ float xq[E], xk[E], xv[E], xp[E];
    __shared__ float qs[E], ks[E];
    int t = threadIdx.x;
    int nl = blockIdx.x;
    size_t base = (size_t)nl * E;
    for (int j = t; j < E; j += 256) {
        xq[j] = query[base + j];
        xk[j] = keys[base + j];
        xv[j] = values[base + j];
        xp[j] = pos[base + j];
    }
    __syncthreads();
#pragma unroll
    for (int cc = 0; cc < 2; cc++) {
        int c = t + cc * 256;
        int h = c >> 6, i = c & 63;
        const float* xqh = xq + (h << 6);
        const float* xkh = xk + (h << 6);
        const float* xvh = xv + (h << 6);
        const float* xph = xp + (h << 6);
        float q_c = dot64(xqh, Wq + (i << 6));
        float k_c = dot64(xkh, Wk + (i << 6));
        float v_c = dot64(xvh, Wv + (i << 6));
        float pq_c = dot64(xph, Wpq + (i << 6));
        float pk_c = dot64(xph, Wpk + (i << 6));
        qv_ws[base + c] = q_c;
        kv_ws[base + c] = k_c;
        vv_ws[base + c] = v_c;
        pq_ws[base + c] = pq_c;
        pk_ws[base + c] = pk_c;
        qs[c] = q_c;
        ks[c] = k_c;
    }
    __syncthreads();
#pragma unroll
    for (int cc = 0; cc < 2; cc++) {
        int c = t + cc * 256;
        int h = c >> 6, d = c & 63;
        float aq = 0.f, ak = 0.f;
        const float* qh = qs + (h << 6);
        const float* kh = ks + (h << 6);
#pragma unroll 8
        for (int i = 0; i < 64; i++) {
            aq = fmaf(qh[i], Wrk[(i << 6) + d], aq);
            ak = fmaf(kh[i], Wrq[(i << 6) + d], ak);
        }
        qrk_ws[base + c] = aq;
        krq_ws[base + c] = ak;
    }
}

// ---------------- K2pre: e_ws = (q.k + pq.pk)*rsqrt2 + mask ----------------
// grid: 512 blocks = n(2) x h(8) x qtile(32 of 8 q). 256 threads, thread = k.
__global__ __launch_bounds__(256) void k2pre(
    const float* __restrict__ qv_ws, const float* __restrict__ kv_ws,
    const float* __restrict__ pq_ws, const float* __restrict__ pk_ws,
    const float* __restrict__ mask, float* __restrict__ e_ws) {
    __shared__ float qs[8 * 64], ps[8 * 64];
    int t = threadIdx.x;
    int b = blockIdx.x;
    int qt = b & 31;
    int h = (b >> 5) & 7;
    int n = b >> 8;
    int nb = n << 8;
    int q0 = qt << 3;
    int k = t;
#pragma unroll
    for (int it = 0; it < 2; it++) {
        int idx = t + (it << 8);
        int q = idx >> 6, d = idx & 63;
        size_t g = (size_t)(nb + q0 + q) * E + (h << 6) + d;
        qs[idx] = qv_ws[g];
        ps[idx] = pq_ws[g];
    }
    __syncthreads();
    const float4* kv4p = (const float4*)(kv_ws + (size_t)(nb + k) * E + (h << 6));
    const float4* pk4p = (const float4*)(pk_ws + (size_t)(nb + k) * E + (h << 6));
    float acc[8];
#pragma unroll
    for (int q = 0; q < 8; q++) acc[q] = 0.f;
#pragma unroll
    for (int d4 = 0; d4 < 16; d4++) {
        float4 kv4 = kv4p[d4];
        float4 pk4 = pk4p[d4];
#pragma unroll
        for (int q = 0; q < 8; q++) {
            float4 q4 = ((const float4*)qs)[(q << 4) + d4];
            float4 p4 = ((const float4*)ps)[(q << 4) + d4];
            float a = acc[q];
            a = fmaf(q4.x, kv4.x, a);
            a = fmaf(q4.y, kv4.y, a);
            a = fmaf(q4.z, kv4.z, a);
            a = fmaf(q4.w, kv4.w, a);
            a = fmaf(p4.x, pk4.x, a);
            a = fmaf(p4.y, pk4.y, a);
            a = fmaf(p4.z, pk4.z, a);
            a = fmaf(p4.w, pk4.w, a);
            acc[q] = a;
        }
    }
    float mk = (1.0f - mask[nb + k]) * (-1e9f);
#pragma unroll
    for (int q = 0; q < 8; q++) {
        e_ws[(size_t)(nb + q0 + q) * (H * L) + (h << 8) + k] = acc[q] * RSQRT2 + mk;
    }
}

// ---------------- K2rel: r_ws = rel . (qrk + krq) * rsqrt2 ----------------
// grid: 512 blocks = n(2) x qtile(16 of 16 q) x kchunk(16 of 16 k). 256 threads.
// 4-deep software pipeline on the rel stream (only HBM-heavy kernel).

#define K2REL_LOAD(R, QK, qi_)                                                  \
    do {                                                                        \
        const int gq_ = nbase + q0 + (qi_);                                     \
        const float* relb_ =                                                    \
            rel + (size_t)gq_ * (size_t)(L * E) + (size_t)kb * E + cq;          \
        _Pragma("unroll") for (int jj = 0; jj < 8; jj++)                        \
            R[jj] = *(const float4*)(relb_ + (size_t)((jj << 1) + rowsel) * E); \
        QK = *(const float4*)(qrk_ws + (size_t)gq_ * E + cq);                   \
    } while (0)

#define K2REL_COMP(R, QK, qi_)                                                  \
    do {                                                                        \
        const int gq_ = nbase + q0 + (qi_);                                     \
        float* rb_ = r_ws + (size_t)gq_ * (H * L) + (h << 8);                   \
        _Pragma("unroll") for (int jj = 0; jj < 8; jj++) {                      \
            float wx = QK.x + kq[jj].x;                                         \
            float wy = QK.y + kq[jj].y;                                         \
            float wz = QK.z + kq[jj].z;                                         \
            float ww = QK.w + kq[jj].w;                                         \
            float p = R[jj].x * wx;                                             \
            p = fmaf(R[jj].y, wy, p);                                           \
            p = fmaf(R[jj].z, wz, p);                                           \
            p = fmaf(R[jj].w, ww, p);                                           \
            p += __shfl_down(p, 8, 16);                                         \
            p += __shfl_down(p, 4, 16);                                         \
            p += __shfl_down(p, 2, 16);                                         \
            p += __shfl_down(p, 1, 16);                                         \
            if (sub == 0) rb_[kb + (jj << 1) + rowsel] = p * RSQRT2;            \
        }                                                                       \
    } while (0)

__global__ __launch_bounds__(256, 2) void k2rel(
    const float* __restrict__ rel, const float* __restrict__ qrk_ws,
    const float* __restrict__ krq_ws, float* __restrict__ r_ws) {
    int t = threadIdx.x;
    int b = blockIdx.x;
    int kc = b & 15;
    int qt = (b >> 4) & 15;
    int n = b >> 8;

    int lane128 = t & 127;
    int rowsel = t >> 7;
    int cq = lane128 << 2;
    int h = lane128 >> 4;
    int sub = t & 15;
    int nbase = n << 8;
    int kb = kc << 4;
    int q0 = qt << 4;

    // resident k-side: krq for my 8 parity rows
    float4 kq[8];
#pragma unroll
    for (int jj = 0; jj < 8; jj++) {
        kq[jj] = *(const float4*)(krq_ws +
                                  (size_t)(nbase + kb + (jj << 1) + rowsel) * E + cq);
    }

    float4 rA[8], rB[8], rC[8], rD[8];
    float4 qA, qB, qC, qD;
    K2REL_LOAD(rA, qA, 0);
    K2REL_LOAD(rB, qB, 1);
    K2REL_LOAD(rC, qC, 2);
#pragma unroll
    for (int qi = 0; qi < 16; qi += 4) {
        K2REL_LOAD(rD, qD, qi + 3);
        K2REL_COMP(rA, qA, qi);
        if (qi < 12) K2REL_LOAD(rA, qA, qi + 4);
        K2REL_COMP(rB, qB, qi + 1);
        if (qi < 12) K2REL_LOAD(rB, qB, qi + 5);
        K2REL_COMP(rC, qC, qi + 2);
        if (qi < 12) K2REL_LOAD(rC, qC, qi + 6);
        K2REL_COMP(rD, qD, qi + 3);
    }
}

// ---------------- K2b: softmax + attn @ V, one block per (n,q) ----------------
__global__ __launch_bounds__(512) void k2b_soft_av(
    const float* __restrict__ e_ws, const float* __restrict__ r_ws,
    const float* __restrict__ vv_ws, float* __restrict__ attn_ws) {
    __shared__ float e_s[H * L];
    __shared__ float PS[4 * E];
    __shared__ float inv_s[H];
    int t = threadIdx.x;
    int nq = blockIdx.x;
    int n = nq >> 8;

    {
        float4 a = ((const float4*)(e_ws + (size_t)nq * (H * L)))[t];
        float4 b = ((const float4*)(r_ws + (size_t)nq * (H * L)))[t];
        a.x += b.x; a.y += b.y; a.z += b.z; a.w += b.w;
        ((float4*)e_s)[t] = a;
    }
    __syncthreads();

    // softmax: one 64-lane wave per head
    {
        int hh = t >> 6;
        int lane = t & 63;
        float* eh = e_s + (hh << 8);
        float m = -INFINITY;
#pragma unroll
        for (int j = 0; j < 4; j++) m = fmaxf(m, eh[lane + (j << 6)]);
#pragma unroll
        for (int off = 32; off > 0; off >>= 1) m = fmaxf(m, __shfl_xor(m, off, 64));
        float s = 0.f;
#pragma unroll
        for (int j = 0; j < 4; j++) {
            int idx = lane + (j << 6);
            float ev = __expf(eh[idx] - m);
            eh[idx] = ev;
            s += ev;
        }
#pragma unroll
        for (int off = 32; off > 0; off >>= 1) s += __shfl_xor(s, off, 64);
        if (lane == 0) inv_s[hh] = 1.0f / s;
    }
    __syncthreads();

    // attn @ V : thread (c4 = 4 channels, kseg = quarter of k-range), float4 loads
    {
        int c4 = (t & 127) << 2;
        int kseg = t >> 7;  // 0..3
        int h1 = c4 >> 6;
        const float* eh = e_s + (h1 << 8) + (kseg << 6);
        const float* vb = vv_ws + ((size_t)(n << 8) + (kseg << 6)) * E + c4;
        float4 acc = {0.f, 0.f, 0.f, 0.f};
#pragma unroll 16
        for (int k = 0; k < 64; k++) {
            float ev = eh[k];
            float4 v4 = *(const float4*)(vb + (size_t)k * E);
            acc.x = fmaf(ev, v4.x, acc.x);
            acc.y = fmaf(ev, v4.y, acc.y);
            acc.z = fmaf(ev, v4.z, acc.z);
            acc.w = fmaf(ev, v4.w, acc.w);
        }
        *(float4*)(PS + kseg * E + c4) = acc;
    }
    __syncthreads();

    {
        int c = t;
        float v = PS[c] + PS[E + c] + PS[2 * E + c] + PS[3 * E + c];
        attn_ws[(size_t)nq * E + c] = v * inv_s[t >> 6];
    }
}

// ---------------- K3: out = attn @ Wout.T + bout (4 rows / block) ----------------
__global__ __launch_bounds__(512) void k3_out(const float* __restrict__ attn_ws,
                                              const float* __restrict__ WoutT,
                                              const float* __restrict__ bout,
                                              float* __restrict__ out) {
    __shared__ float As[4 * E];
    int t = threadIdx.x;
    int r0 = blockIdx.x << 2;
    for (int j = t; j < 4 * E; j += 512) As[j] = attn_ws[(size_t)r0 * E + j];
    __syncthreads();
    float b0 = bout[t];
    float a0 = b0, a1 = b0, a2 = b0, a3 = b0;
#pragma unroll 8
    for (int c = 0; c < E; c++) {
        float w = WoutT[((size_t)c << 9) + t];
        a0 = fmaf(As[c], w, a0);
        a1 = fmaf(As[E + c], w, a1);
        a2 = fmaf(As[2 * E + c], w, a2);
        a3 = fmaf(As[3 * E + c], w, a3);
    }
    out[(size_t)(r0 + 0) * E + t] = a0;
    out[(size_t)(r0 + 1) * E + t] = a1;
    out[(size_t)(r0 + 2) * E + t] = a2;
    out[(size_t)(r0 + 3) * E + t] = a3;
}

extern "C" void kernel_launch(void* const* d_in, const int* in_sizes, int n_in,
                              void* d_out, int out_size, void* d_ws, size_t ws_size,
                              hipStream_t stream) {
    const float* values = (const float*)d_in[0];
    const float* keys = (const float*)d_in[1];
    const float* query = (const float*)d_in[2];
    const float* pos = (const float*)d_in[3];
    const float* rel = (const float*)d_in[4];
    const float* mask = (const float*)d_in[5];
    const float* Wv = (const float*)d_in[6];
    const float* Wk = (const float*)d_in[7];
    const float* Wq = (const float*)d_in[8];
    const float* Wpq = (const float*)d_in[9];
    const float* Wpk = (const float*)d_in[10];
    const float* Wrk = (const float*)d_in[11];
    const float* Wrq = (const float*)d_in[12];
    const float* Wout = (const float*)d_in[13];
    const float* bout = (const float*)d_in[14];
    float* out = (float*)d_out;

    float* ws = (float*)d_ws;
    const size_t SZ = (size_t)NL * E;  // 262144 floats = 1 MB
    float* qv_ws = ws + 0 * SZ;
    float* kv_ws = ws + 1 * SZ;
    float* vv_ws = ws + 2 * SZ;
    float* pq_ws = ws + 3 * SZ;
    float* pk_ws = ws + 4 * SZ;
    float* qrk_ws = ws + 5 * SZ;
    float* krq_ws = ws + 6 * SZ;
    float* attn_ws = ws + 7 * SZ;
    float* WoutT = ws + 8 * SZ;
    float* e_ws = ws + 9 * SZ;                          // NL*H*L floats = 4 MB
    float* r_ws = e_ws + (size_t)NL * (H * L);          // NL*H*L floats = 4 MB

    k0_transpose<<<64, 256, 0, stream>>>(Wout, WoutT);
    k1_proj<<<NL, 256, 0, stream>>>(values, keys, query, pos, Wv, Wk, Wq, Wpq,
                                    Wpk, Wrk, Wrq, qv_ws, kv_ws, vv_ws, pq_ws,
                                    pk_ws, qrk_ws, krq_ws);
    k2pre<<<512, 256, 0, stream>>>(qv_ws, kv_ws, pq_ws, pk_ws, mask, e_ws);
    k2rel<<<512, 256, 0, stream>>>(rel, qrk_ws, krq_ws, r_ws);
    k2b_soft_av<<<NL, 512, 0, stream>>>(e_ws, r_ws, vv_ws, attn_ws);
    k3_out<<<NL / 4, 512, 0, stream>>>(attn_ws, WoutT, bout, out);
}

// Round 2
// 494.117 us; speedup vs baseline: 1.0293x; 1.0293x over previous
//
#include <hip/hip_runtime.h>
#include <hip/hip_bf16.h>

#define NB 2
#define L 256
#define H 8
#define D 64
#define E 512
#define NL (NB * L)
#define RSQRT2 0.70710678118654752f

// ---------------- K0: transpose Wout [E][E] -> WoutT [c][e] ----------------
__global__ __launch_bounds__(256) void k0_transpose(const float* __restrict__ Wout,
                                                    float* __restrict__ WoutT) {
    __shared__ float tile[64][65];
    int t = threadIdx.x;
    int bi = blockIdx.x >> 3;   // e-tile
    int bj = blockIdx.x & 7;    // c-tile
    int tx = t & 63, ty = t >> 6;  // ty 0..3
#pragma unroll
    for (int m = 0; m < 16; m++) {
        int el = ty + (m << 2);
        tile[el][tx] = Wout[(size_t)(bi * 64 + el) * E + bj * 64 + tx];
    }
    __syncthreads();
#pragma unroll
    for (int m = 0; m < 16; m++) {
        int cl = ty + (m << 2);
        WoutT[(size_t)(bj * 64 + cl) * E + bi * 64 + tx] = tile[tx][cl];
    }
}

// ---------------- K1: per-(n,l) projections ----------------
__device__ __forceinline__ float dot64(const float* __restrict__ a,
                                       const float* __restrict__ w) {
    const float4* a4 = (const float4*)a;
    const float4* w4 = (const float4*)w;
    float acc = 0.f;
#pragma unroll
    for (int j = 0; j < 16; j++) {
        float4 x = a4[j], y = w4[j];
        acc = fmaf(x.x, y.x, acc);
        acc = fmaf(x.y, y.y, acc);
        acc = fmaf(x.z, y.z, acc);
        acc = fmaf(x.w, y.w, acc);
    }
    return acc;
}

__global__ __launch_bounds__(256) void k1_proj(
    const float* __restrict__ values, const float* __restrict__ keys,
    const float* __restrict__ query, const float* __restrict__ pos,
    const float* __restrict__ Wv, const float* __restrict__ Wk,
    const float* __restrict__ Wq, const float* __restrict__ Wpq,
    const float* __restrict__ Wpk, const float* __restrict__ Wrk,
    const float* __restrict__ Wrq,
    float* __restrict__ qv_ws, float* __restrict__ kv_ws,
    float* __restrict__ vv_ws, float* __restrict__ pq_ws,
    float* __restrict__ pk_ws, float* __restrict__ qrk_ws,
    float* __restrict__ krq_ws) {
    __shared__ float xq[E], xk[E], xv[E], xp[E];
    __shared__ float qs[E], ks[E];
    int t = threadIdx.x;
    int nl = blockIdx.x;
    size_t base = (size_t)nl * E;
    for (int j = t; j < E; j += 256) {
        xq[j] = query[base + j];
        xk[j] = keys[base + j];
        xv[j] = values[base + j];
        xp[j] = pos[base + j];
    }
    __syncthreads();
#pragma unroll
    for (int cc = 0; cc < 2; cc++) {
        int c = t + cc * 256;
        int h = c >> 6, i = c & 63;
        const float* xqh = xq + (h << 6);
        const float* xkh = xk + (h << 6);
        const float* xvh = xv + (h << 6);
        const float* xph = xp + (h << 6);
        float q_c = dot64(xqh, Wq + (i << 6));
        float k_c = dot64(xkh, Wk + (i << 6));
        float v_c = dot64(xvh, Wv + (i << 6));
        float pq_c = dot64(xph, Wpq + (i << 6));
        float pk_c = dot64(xph, Wpk + (i << 6));
        qv_ws[base + c] = q_c;
        kv_ws[base + c] = k_c;
        vv_ws[base + c] = v_c;
        pq_ws[base + c] = pq_c;
        pk_ws[base + c] = pk_c;
        qs[c] = q_c;
        ks[c] = k_c;
    }
    __syncthreads();
#pragma unroll
    for (int cc = 0; cc < 2; cc++) {
        int c = t + cc * 256;
        int h = c >> 6, d = c & 63;
        float aq = 0.f, ak = 0.f;
        const float* qh = qs + (h << 6);
        const float* kh = ks + (h << 6);
#pragma unroll 8
        for (int i = 0; i < 64; i++) {
            aq = fmaf(qh[i], Wrk[(i << 6) + d], aq);
            ak = fmaf(kh[i], Wrq[(i << 6) + d], ak);
        }
        qrk_ws[base + c] = aq;
        krq_ws[base + c] = ak;
    }
}

// ---------------- K2pre: e_ws = (q.k + pq.pk)*rsqrt2 + mask ----------------
// grid: 512 blocks = n(2) x h(8) x qtile(32 of 8 q). 256 threads, thread = k.
__global__ __launch_bounds__(256) void k2pre(
    const float* __restrict__ qv_ws, const float* __restrict__ kv_ws,
    const float* __restrict__ pq_ws, const float* __restrict__ pk_ws,
    const float* __restrict__ mask, float* __restrict__ e_ws) {
    __shared__ float qs[8 * 64], ps[8 * 64];
    int t = threadIdx.x;
    int b = blockIdx.x;
    int qt = b & 31;
    int h = (b >> 5) & 7;
    int n = b >> 8;
    int nb = n << 8;
    int q0 = qt << 3;
    int k = t;
#pragma unroll
    for (int it = 0; it < 2; it++) {
        int idx = t + (it << 8);
        int q = idx >> 6, d = idx & 63;
        size_t g = (size_t)(nb + q0 + q) * E + (h << 6) + d;
        qs[idx] = qv_ws[g];
        ps[idx] = pq_ws[g];
    }
    __syncthreads();
    const float4* kv4p = (const float4*)(kv_ws + (size_t)(nb + k) * E + (h << 6));
    const float4* pk4p = (const float4*)(pk_ws + (size_t)(nb + k) * E + (h << 6));
    float acc[8];
#pragma unroll
    for (int q = 0; q < 8; q++) acc[q] = 0.f;
#pragma unroll
    for (int d4 = 0; d4 < 16; d4++) {
        float4 kv4 = kv4p[d4];
        float4 pk4 = pk4p[d4];
#pragma unroll
        for (int q = 0; q < 8; q++) {
            float4 q4 = ((const float4*)qs)[(q << 4) + d4];
            float4 p4 = ((const float4*)ps)[(q << 4) + d4];
            float a = acc[q];
            a = fmaf(q4.x, kv4.x, a);
            a = fmaf(q4.y, kv4.y, a);
            a = fmaf(q4.z, kv4.z, a);
            a = fmaf(q4.w, kv4.w, a);
            a = fmaf(p4.x, pk4.x, a);
            a = fmaf(p4.y, pk4.y, a);
            a = fmaf(p4.z, pk4.z, a);
            a = fmaf(p4.w, pk4.w, a);
            acc[q] = a;
        }
    }
    float mk = (1.0f - mask[nb + k]) * (-1e9f);
#pragma unroll
    for (int q = 0; q < 8; q++) {
        e_ws[(size_t)(nb + q0 + q) * (H * L) + (h << 8) + k] = acc[q] * RSQRT2 + mk;
    }
}

// ---------------- K2f: fused rel-energy + softmax + attn@V ----------------
// grid: 512 blocks = one per (n,q). 256 threads.
// Each block streams its own 512 KB slab of rel exactly once (the only HBM
// stream in the whole pipeline), double-buffered 2-deep with named register
// buffers; energies accumulate into LDS; softmax + AV happen in-block.

#define K2F_LOAD(RR, RK, b_)                                              \
    do {                                                                  \
        _Pragma("unroll") for (int jj = 0; jj < 8; jj++) {                \
            int k_ = ((b_) << 4) + (jj << 1) + rowsel;                    \
            RR[jj] = *(const float4*)(relb + ((size_t)k_ << 9) + cq);     \
            RK[jj] = *(const float4*)(krqb + ((size_t)k_ << 9) + cq);     \
        }                                                                 \
    } while (0)

#define K2F_COMP(RR, RK, b_)                                              \
    do {                                                                  \
        _Pragma("unroll") for (int jj = 0; jj < 8; jj++) {                \
            float wx = qrk4.x + RK[jj].x;                                 \
            float wy = qrk4.y + RK[jj].y;                                 \
            float wz = qrk4.z + RK[jj].z;                                 \
            float ww = qrk4.w + RK[jj].w;                                 \
            float p = RR[jj].x * wx;                                      \
            p = fmaf(RR[jj].y, wy, p);                                    \
            p = fmaf(RR[jj].z, wz, p);                                    \
            p = fmaf(RR[jj].w, ww, p);                                    \
            p += __shfl_down(p, 8, 16);                                   \
            p += __shfl_down(p, 4, 16);                                   \
            p += __shfl_down(p, 2, 16);                                   \
            p += __shfl_down(p, 1, 16);                                   \
            if (sub == 0) {                                               \
                int k_ = ((b_) << 4) + (jj << 1) + rowsel;                \
                r_s[(h << 8) + k_] = p * RSQRT2;                          \
            }                                                             \
        }                                                                 \
    } while (0)

__global__ __launch_bounds__(256, 2) void k2f(
    const float* __restrict__ rel, const float* __restrict__ qrk_ws,
    const float* __restrict__ krq_ws, const float* __restrict__ e_ws,
    const float* __restrict__ vv_ws, float* __restrict__ attn_ws) {
    __shared__ float e_s[H * L];   // staged pre-energies, later exp(P)
    __shared__ float r_s[H * L];   // rel contributions (write-once per (h,k))
    __shared__ float PS[2 * E];
    __shared__ float inv_s[H];
    int t = threadIdx.x;
    int nq = blockIdx.x;           // n*256 + q
    int n = nq >> 8;

    // stage pre-computed energies (q.k + pq.pk + mask), 2048 floats
    {
        const float4* src = (const float4*)(e_ws + (size_t)nq * (H * L));
        ((float4*)e_s)[t] = src[t];
        ((float4*)e_s)[t + 256] = src[t + 256];
    }

    int lane128 = t & 127;
    int rowsel = t >> 7;           // k parity
    int cq = lane128 << 2;         // channel base (4 floats), 0..508
    int h = lane128 >> 4;          // head
    int sub = t & 15;              // position within the 16-lane head-group

    const float* relb = rel + (((size_t)nq) << 8) * E;        // + (k<<9)+cq
    const float* krqb = krq_ws + (((size_t)(n << 8))) * E;    // + (k<<9)+cq
    float4 qrk4 = *(const float4*)(qrk_ws + (size_t)nq * E + cq);

    float4 rAr[8], rAk[8], rBr[8], rBk[8];
    K2F_LOAD(rAr, rAk, 0);
#pragma unroll
    for (int b = 0; b < 16; b += 2) {
        K2F_LOAD(rBr, rBk, b + 1);
        K2F_COMP(rAr, rAk, b);
        if (b + 2 < 16) K2F_LOAD(rAr, rAk, b + 2);
        K2F_COMP(rBr, rBk, b + 1);
    }
    __syncthreads();

    // softmax: 32 threads per head; head group aligns with wave halves.
    {
        int hh = t >> 5;           // 0..7
        int l32 = t & 31;
        float* eh = e_s + (hh << 8);
        const float* rh = r_s + (hh << 8);
        float x[8];
        float m = -INFINITY;
#pragma unroll
        for (int j = 0; j < 8; j++) {
            int idx = l32 + (j << 5);
            x[j] = eh[idx] + rh[idx];
            m = fmaxf(m, x[j]);
        }
#pragma unroll
        for (int off = 16; off > 0; off >>= 1) m = fmaxf(m, __shfl_xor(m, off, 32));
        float s = 0.f;
#pragma unroll
        for (int j = 0; j < 8; j++) {
            int idx = l32 + (j << 5);
            float ev = __expf(x[j] - m);
            eh[idx] = ev;
            s += ev;
        }
#pragma unroll
        for (int off = 16; off > 0; off >>= 1) s += __shfl_xor(s, off, 32);
        if (l32 == 0) inv_s[hh] = 1.0f / s;
    }
    __syncthreads();

    // attn @ V: 128 threads span channels, 2 k-segments of 128
    {
        int c4 = (t & 127) << 2;
        int kseg = t >> 7;         // 0 or 1
        int h1 = c4 >> 6;
        const float* eh = e_s + (h1 << 8) + (kseg << 7);
        const float* vb = vv_ws + ((size_t)((n << 8) + (kseg << 7))) * E + c4;
        float4 acc = {0.f, 0.f, 0.f, 0.f};
#pragma unroll 16
        for (int k = 0; k < 128; k++) {
            float ev = eh[k];
            float4 v4 = *(const float4*)(vb + ((size_t)k << 9));
            acc.x = fmaf(ev, v4.x, acc.x);
            acc.y = fmaf(ev, v4.y, acc.y);
            acc.z = fmaf(ev, v4.z, acc.z);
            acc.w = fmaf(ev, v4.w, acc.w);
        }
        *(float4*)(PS + kseg * E + c4) = acc;
    }
    __syncthreads();

    {
        float v0 = PS[t] + PS[E + t];
        attn_ws[(size_t)nq * E + t] = v0 * inv_s[t >> 6];
        float v1 = PS[256 + t] + PS[E + 256 + t];
        attn_ws[(size_t)nq * E + 256 + t] = v1 * inv_s[(256 + t) >> 6];
    }
}

// ---------------- K3: out = attn @ Wout.T + bout (4 rows / block) ----------------
__global__ __launch_bounds__(512) void k3_out(const float* __restrict__ attn_ws,
                                              const float* __restrict__ WoutT,
                                              const float* __restrict__ bout,
                                              float* __restrict__ out) {
    __shared__ float As[4 * E];
    int t = threadIdx.x;
    int r0 = blockIdx.x << 2;
    for (int j = t; j < 4 * E; j += 512) As[j] = attn_ws[(size_t)r0 * E + j];
    __syncthreads();
    float b0 = bout[t];
    float a0 = b0, a1 = b0, a2 = b0, a3 = b0;
#pragma unroll 8
    for (int c = 0; c < E; c++) {
        float w = WoutT[((size_t)c << 9) + t];
        a0 = fmaf(As[c], w, a0);
        a1 = fmaf(As[E + c], w, a1);
        a2 = fmaf(As[2 * E + c], w, a2);
        a3 = fmaf(As[3 * E + c], w, a3);
    }
    out[(size_t)(r0 + 0) * E + t] = a0;
    out[(size_t)(r0 + 1) * E + t] = a1;
    out[(size_t)(r0 + 2) * E + t] = a2;
    out[(size_t)(r0 + 3) * E + t] = a3;
}

extern "C" void kernel_launch(void* const* d_in, const int* in_sizes, int n_in,
                              void* d_out, int out_size, void* d_ws, size_t ws_size,
                              hipStream_t stream) {
    const float* values = (const float*)d_in[0];
    const float* keys = (const float*)d_in[1];
    const float* query = (const float*)d_in[2];
    const float* pos = (const float*)d_in[3];
    const float* rel = (const float*)d_in[4];
    const float* mask = (const float*)d_in[5];
    const float* Wv = (const float*)d_in[6];
    const float* Wk = (const float*)d_in[7];
    const float* Wq = (const float*)d_in[8];
    const float* Wpq = (const float*)d_in[9];
    const float* Wpk = (const float*)d_in[10];
    const float* Wrk = (const float*)d_in[11];
    const float* Wrq = (const float*)d_in[12];
    const float* Wout = (const float*)d_in[13];
    const float* bout = (const float*)d_in[14];
    float* out = (float*)d_out;

    float* ws = (float*)d_ws;
    const size_t SZ = (size_t)NL * E;  // 262144 floats = 1 MB
    float* qv_ws = ws + 0 * SZ;
    float* kv_ws = ws + 1 * SZ;
    float* vv_ws = ws + 2 * SZ;
    float* pq_ws = ws + 3 * SZ;
    float* pk_ws = ws + 4 * SZ;
    float* qrk_ws = ws + 5 * SZ;
    float* krq_ws = ws + 6 * SZ;
    float* attn_ws = ws + 7 * SZ;
    float* WoutT = ws + 8 * SZ;
    float* e_ws = ws + 9 * SZ;  // NL * H * L floats = 4 MB

    k0_transpose<<<64, 256, 0, stream>>>(Wout, WoutT);
    k1_proj<<<NL, 256, 0, stream>>>(values, keys, query, pos, Wv, Wk, Wq, Wpq,
                                    Wpk, Wrk, Wrq, qv_ws, kv_ws, vv_ws, pq_ws,
                                    pk_ws, qrk_ws, krq_ws);
    k2pre<<<512, 256, 0, stream>>>(qv_ws, kv_ws, pq_ws, pk_ws, mask, e_ws);
    k2f<<<512, 256, 0, stream>>>(rel, qrk_ws, krq_ws, e_ws, vv_ws, attn_ws);
    k3_out<<<NL / 4, 512, 0, stream>>>(attn_ws, WoutT, bout, out);
}